// Round 2
// baseline (634.673 us; speedup 1.0000x reference)
//
#include <hip/hip_runtime.h>
#include <math.h>

#define NN 30000
#define NE 480000

__device__ __forceinline__ float lrelu(float v) { return v > 0.0f ? v : v * 0.02f; }

// ---------------- CSR build ----------------

__global__ void k_count(const int* __restrict__ ei, int* __restrict__ cnt) {
    int e = blockIdx.x * 256 + threadIdx.x;
    if (e < NE) atomicAdd(&cnt[ei[NE + e]], 1);
}

__global__ void k_dinv(const int* __restrict__ cnt, float* __restrict__ dinv) {
    int i = blockIdx.x * 256 + threadIdx.x;
    if (i < NN) dinv[i] = 1.0f / sqrtf((float)(cnt[i] + 1));  // +1 self loop
}

__global__ void k_scan(const int* __restrict__ cnt, int* __restrict__ row_ptr,
                       int* __restrict__ cursor) {
    __shared__ int sd[1024];
    int tid = threadIdx.x;
    int running = 0;
    for (int base = 0; base < NN; base += 1024) {
        int i = base + tid;
        int v = (i < NN) ? cnt[i] : 0;
        sd[tid] = v;
        __syncthreads();
        for (int off = 1; off < 1024; off <<= 1) {
            int t = (tid >= off) ? sd[tid - off] : 0;
            __syncthreads();
            sd[tid] += t;
            __syncthreads();
        }
        int incl = sd[tid];
        int total = sd[1023];
        __syncthreads();
        if (i < NN) {
            int excl = running + incl - v;
            row_ptr[i] = excl;
            cursor[i] = excl;
        }
        running += total;
    }
    if (tid == 0) row_ptr[NN] = running;
}

__global__ void k_fill(const int* __restrict__ ei, const float* __restrict__ dinv,
                       int* __restrict__ cursor, int2* __restrict__ csr) {
    int e = blockIdx.x * 256 + threadIdx.x;
    if (e < NE) {
        int s = ei[e];
        int d = ei[NE + e];
        int pos = atomicAdd(&cursor[d], 1);
        float w = dinv[s] * dinv[d];
        csr[pos] = make_int2(s, __float_as_int(w));
    }
}

// ---------------- aggregation: out = D^-1/2 (A+I) D^-1/2 * (maybe-leaky h) ----------------

template <int C, bool LEAKY>
__launch_bounds__(256)
__global__ void k_agg(const float* __restrict__ h, const int* __restrict__ row_ptr,
                      const int2* __restrict__ csr, const float* __restrict__ dinv,
                      float* __restrict__ out) {
    constexpr int TPN = C / 4;        // threads per node (float4 each)
    constexpr int NPB = 256 / TPN;    // nodes per block
    int node = blockIdx.x * NPB + threadIdx.x / TPN;
    if (node >= NN) return;
    int c = (threadIdx.x % TPN) * 4;
    float di = dinv[node];
    float w0 = di * di;
    float4 hv = *(const float4*)&h[(size_t)node * C + c];
    if (LEAKY) { hv.x = lrelu(hv.x); hv.y = lrelu(hv.y); hv.z = lrelu(hv.z); hv.w = lrelu(hv.w); }
    float4 acc = make_float4(hv.x * w0, hv.y * w0, hv.z * w0, hv.w * w0);
    int e1 = row_ptr[node + 1];
    for (int e = row_ptr[node]; e < e1; ++e) {
        int2 sw = csr[e];
        float w = __int_as_float(sw.y);
        float4 v = *(const float4*)&h[(size_t)sw.x * C + c];
        if (LEAKY) { v.x = lrelu(v.x); v.y = lrelu(v.y); v.z = lrelu(v.z); v.w = lrelu(v.w); }
        acc.x = fmaf(v.x, w, acc.x);
        acc.y = fmaf(v.y, w, acc.y);
        acc.z = fmaf(v.z, w, acc.z);
        acc.w = fmaf(v.w, w, acc.w);
    }
    *(float4*)&out[(size_t)node * C + c] = acc;
}

// ---------------- fp32 GEMM: out[N,128] = A[N,K] @ W[K,128] + b ----------------
// block: 256 threads, 32-row tile; thread (tx,ty) computes rows ty*4..+3, cols tx*4..+3

template <int K>
__launch_bounds__(256)
__global__ void k_gemm(const float* __restrict__ A, const float* __restrict__ W,
                       const float* __restrict__ bias, float* __restrict__ out) {
    __shared__ float Ws[64 * 128];   // one 64-k chunk of W
    __shared__ float hs[32 * K];     // 32-row tile of A
    constexpr int K4 = K / 4;
    int tid = threadIdx.x;
    int row0 = blockIdx.x * 32;

    for (int i = tid; i < 32 * K4; i += 256) {
        int r = i / K4;
        int gr = row0 + r;
        float4 v = (gr < NN) ? *(const float4*)&A[(size_t)gr * K + (i % K4) * 4]
                             : make_float4(0.f, 0.f, 0.f, 0.f);
        *(float4*)&hs[i * 4] = v;
    }

    int tx = tid & 31, ty = tid >> 5;
    float4 acc[4];
    #pragma unroll
    for (int i = 0; i < 4; i++) acc[i] = make_float4(0.f, 0.f, 0.f, 0.f);

    for (int kb = 0; kb < K; kb += 64) {
        __syncthreads();  // hs ready (iter 0) / previous chunk's compute done
        for (int i = tid; i < 64 * 32; i += 256)  // 64*128/4 float4s
            *(float4*)&Ws[i * 4] = *(const float4*)&W[(size_t)kb * 128 + i * 4];
        __syncthreads();

        #pragma unroll
        for (int k0 = 0; k0 < 64; k0 += 4) {
            float4 hr[4], wr[4];
            #pragma unroll
            for (int i = 0; i < 4; i++) hr[i] = *(const float4*)&hs[(ty * 4 + i) * K + kb + k0];
            #pragma unroll
            for (int j = 0; j < 4; j++) wr[j] = *(const float4*)&Ws[(k0 + j) * 128 + tx * 4];
            #pragma unroll
            for (int i = 0; i < 4; i++) {
                acc[i].x = fmaf(hr[i].x, wr[0].x, acc[i].x);
                acc[i].y = fmaf(hr[i].x, wr[0].y, acc[i].y);
                acc[i].z = fmaf(hr[i].x, wr[0].z, acc[i].z);
                acc[i].w = fmaf(hr[i].x, wr[0].w, acc[i].w);
                acc[i].x = fmaf(hr[i].y, wr[1].x, acc[i].x);
                acc[i].y = fmaf(hr[i].y, wr[1].y, acc[i].y);
                acc[i].z = fmaf(hr[i].y, wr[1].z, acc[i].z);
                acc[i].w = fmaf(hr[i].y, wr[1].w, acc[i].w);
                acc[i].x = fmaf(hr[i].z, wr[2].x, acc[i].x);
                acc[i].y = fmaf(hr[i].z, wr[2].y, acc[i].y);
                acc[i].z = fmaf(hr[i].z, wr[2].z, acc[i].z);
                acc[i].w = fmaf(hr[i].z, wr[2].w, acc[i].w);
                acc[i].x = fmaf(hr[i].w, wr[3].x, acc[i].x);
                acc[i].y = fmaf(hr[i].w, wr[3].y, acc[i].y);
                acc[i].z = fmaf(hr[i].w, wr[3].z, acc[i].z);
                acc[i].w = fmaf(hr[i].w, wr[3].w, acc[i].w);
            }
        }
    }

    float4 bv = *(const float4*)&bias[tx * 4];
    #pragma unroll
    for (int i = 0; i < 4; i++) {
        int gr = row0 + ty * 4 + i;
        if (gr < NN)
            *(float4*)&out[(size_t)gr * 128 + tx * 4] =
                make_float4(acc[i].x + bv.x, acc[i].y + bv.y, acc[i].z + bv.z, acc[i].w + bv.w);
    }
}

// ---------------- final: u = leaky(h) @ Wout[128,3] ----------------

__launch_bounds__(256)
__global__ void k_out_gemm(const float* __restrict__ h, const float* __restrict__ Wout,
                           float* __restrict__ u) {
    __shared__ float Ws[128 * 3];
    int tid = threadIdx.x;
    for (int i = tid; i < 384; i += 256) Ws[i] = Wout[i];
    __syncthreads();
    int row = blockIdx.x * 8 + (tid >> 5);
    int lane = tid & 31;
    if (row >= NN) return;
    float4 v = *(const float4*)&h[(size_t)row * 128 + lane * 4];
    v.x = lrelu(v.x); v.y = lrelu(v.y); v.z = lrelu(v.z); v.w = lrelu(v.w);
    int k = lane * 4;
    float a0 = v.x * Ws[k * 3 + 0] + v.y * Ws[(k + 1) * 3 + 0] +
               v.z * Ws[(k + 2) * 3 + 0] + v.w * Ws[(k + 3) * 3 + 0];
    float a1 = v.x * Ws[k * 3 + 1] + v.y * Ws[(k + 1) * 3 + 1] +
               v.z * Ws[(k + 2) * 3 + 1] + v.w * Ws[(k + 3) * 3 + 1];
    float a2 = v.x * Ws[k * 3 + 2] + v.y * Ws[(k + 1) * 3 + 2] +
               v.z * Ws[(k + 2) * 3 + 2] + v.w * Ws[(k + 3) * 3 + 2];
    for (int off = 16; off > 0; off >>= 1) {
        a0 += __shfl_down(a0, off, 32);
        a1 += __shfl_down(a1, off, 32);
        a2 += __shfl_down(a2, off, 32);
    }
    if (lane == 0) {
        u[(size_t)row * 3 + 0] = a0;
        u[(size_t)row * 3 + 1] = a1;
        u[(size_t)row * 3 + 2] = a2;
    }
}

// ---------------- final aggregate (3 ch) + bias + tanh*0.5 ----------------

__global__ void k_agg_out(const float* __restrict__ u, const int* __restrict__ row_ptr,
                          const int2* __restrict__ csr, const float* __restrict__ dinv,
                          const float* __restrict__ bout, float* __restrict__ out) {
    int node = blockIdx.x * 256 + threadIdx.x;
    if (node >= NN) return;
    float di = dinv[node], w0 = di * di;
    float a0 = u[(size_t)node * 3 + 0] * w0;
    float a1 = u[(size_t)node * 3 + 1] * w0;
    float a2 = u[(size_t)node * 3 + 2] * w0;
    int e1 = row_ptr[node + 1];
    for (int e = row_ptr[node]; e < e1; ++e) {
        int2 sw = csr[e];
        float w = __int_as_float(sw.y);
        const float* us = &u[(size_t)sw.x * 3];
        a0 = fmaf(us[0], w, a0);
        a1 = fmaf(us[1], w, a1);
        a2 = fmaf(us[2], w, a2);
    }
    out[(size_t)node * 3 + 0] = tanhf(a0 + bout[0]) * 0.5f;
    out[(size_t)node * 3 + 1] = tanhf(a1 + bout[1]) * 0.5f;
    out[(size_t)node * 3 + 2] = tanhf(a2 + bout[2]) * 0.5f;
}

// ---------------- launch ----------------

extern "C" void kernel_launch(void* const* d_in, const int* in_sizes, int n_in,
                              void* d_out, int out_size, void* d_ws, size_t ws_size,
                              hipStream_t stream) {
    const float* x        = (const float*)d_in[0];
    const int*   ei       = (const int*)d_in[1];   // int32: [2, NE] row-major
    const float* W0       = (const float*)d_in[2];
    const float* b0       = (const float*)d_in[3];
    const float* Wh       = (const float*)d_in[4];
    const float* bh       = (const float*)d_in[5];
    const float* Wout     = (const float*)d_in[6];
    const float* bout     = (const float*)d_in[7];
    float* out            = (float*)d_out;

    char* ws = (char*)d_ws;
    float* bufA   = (float*)(ws + 0);              // NN*128 floats = 15,360,000 B
    float* bufB   = (float*)(ws + 15360000);       // NN*128 floats
    float* dinv   = (float*)(ws + 30720000);       // NN floats
    int*   cnt    = (int*)  (ws + 30840000);       // NN ints
    int*   row_ptr= (int*)  (ws + 30960000);       // NN+1 ints (padded)
    int*   cursor = (int*)  (ws + 31080064);       // NN ints
    int2*  csr    = (int2*) (ws + 31200064);       // NE int2 = 3,840,000 B

    hipMemsetAsync(cnt, 0, NN * sizeof(int), stream);
    k_count<<<(NE + 255) / 256, 256, 0, stream>>>(ei, cnt);
    k_dinv<<<(NN + 255) / 256, 256, 0, stream>>>(cnt, dinv);
    k_scan<<<1, 1024, 0, stream>>>(cnt, row_ptr, cursor);
    k_fill<<<(NE + 255) / 256, 256, 0, stream>>>(ei, dinv, cursor, csr);

    // layer 0: h1 = (A_hat x) @ W0 + b0     (aggregate-first: 64ch gather)
    k_agg<64, false><<<NN / 16, 256, 0, stream>>>(x, row_ptr, csr, dinv, bufA);
    k_gemm<64><<<(NN + 31) / 32, 256, 0, stream>>>(bufA, W0, b0, bufB);

    // hidden layers: h = (A_hat leaky(h)) @ Wh[i] + bh[i]
    for (int i = 0; i < 6; i++) {
        k_agg<128, true><<<NN / 8, 256, 0, stream>>>(bufB, row_ptr, csr, dinv, bufA);
        k_gemm<128><<<(NN + 31) / 32, 256, 0, stream>>>(bufA, Wh + (size_t)i * 128 * 128,
                                                        bh + (size_t)i * 128, bufB);
    }

    // final: out = tanh(A_hat (leaky(h) @ Wout) + bout) * 0.5   (GEMM-first: 3ch gather)
    k_out_gemm<<<(NN + 7) / 8, 256, 0, stream>>>(bufB, Wout, bufA /* u: NN x 3 */);
    k_agg_out<<<(NN + 255) / 256, 256, 0, stream>>>(bufA, row_ptr, csr, dinv, bout, out);
}

// Round 3
// 590.358 us; speedup vs baseline: 1.0751x; 1.0751x over previous
//
#include <hip/hip_runtime.h>
#include <math.h>

#define NN 30000
#define NE 480000
#define NB 118  // ceil(NN/256)

__device__ __forceinline__ float lrelu(float v) { return v > 0.0f ? v : v * 0.02f; }

// ---------------- CSR build ----------------

__global__ void k_count(const int* __restrict__ ei, int* __restrict__ cnt) {
    int e = blockIdx.x * 256 + threadIdx.x;
    if (e < NE) atomicAdd(&cnt[ei[NE + e]], 1);
}

// phase 1: per-block totals of cnt, plus dinv (fused)
__global__ void k_scan1(const int* __restrict__ cnt, int* __restrict__ bsum,
                        float* __restrict__ dinv) {
    __shared__ int sd[256];
    int tid = threadIdx.x;
    int i = blockIdx.x * 256 + tid;
    int v = (i < NN) ? cnt[i] : 0;
    if (i < NN) dinv[i] = 1.0f / sqrtf((float)(v + 1));  // +1 self loop
    sd[tid] = v;
    __syncthreads();
    for (int off = 128; off > 0; off >>= 1) {
        if (tid < off) sd[tid] += sd[tid + off];
        __syncthreads();
    }
    if (tid == 0) bsum[blockIdx.x] = sd[0];
}

// phase 2: exclusive scan of NB block sums (single tiny block)
__global__ void k_scan2(const int* __restrict__ bsum, int* __restrict__ boff) {
    __shared__ int sd[128];
    int tid = threadIdx.x;  // 128 threads >= NB
    int v = (tid < NB) ? bsum[tid] : 0;
    sd[tid] = v;
    __syncthreads();
    for (int off = 1; off < 128; off <<= 1) {
        int t = (tid >= off) ? sd[tid - off] : 0;
        __syncthreads();
        sd[tid] += t;
        __syncthreads();
    }
    if (tid < NB) boff[tid] = sd[tid] - v;  // exclusive
}

// phase 3: within-block inclusive scan + offset -> row_ptr/cursor
__global__ void k_scan3(const int* __restrict__ cnt, const int* __restrict__ boff,
                        int* __restrict__ row_ptr, int* __restrict__ cursor) {
    __shared__ int sd[256];
    int tid = threadIdx.x;
    int i = blockIdx.x * 256 + tid;
    int v = (i < NN) ? cnt[i] : 0;
    sd[tid] = v;
    __syncthreads();
    for (int off = 1; off < 256; off <<= 1) {
        int t = (tid >= off) ? sd[tid - off] : 0;
        __syncthreads();
        sd[tid] += t;
        __syncthreads();
    }
    if (i < NN) {
        int excl = boff[blockIdx.x] + sd[tid] - v;
        row_ptr[i] = excl;
        cursor[i] = excl;
        if (i == NN - 1) row_ptr[NN] = excl + v;
    }
}

__global__ void k_fill(const int* __restrict__ ei, const float* __restrict__ dinv,
                       int* __restrict__ cursor, int2* __restrict__ csr) {
    int e = blockIdx.x * 256 + threadIdx.x;
    if (e < NE) {
        int s = ei[e];
        int d = ei[NE + e];
        int pos = atomicAdd(&cursor[d], 1);
        float w = dinv[s] * dinv[d];
        csr[pos] = make_int2(s, __float_as_int(w));
    }
}

// ---------------- aggregation: out = D^-1/2 (A+I) D^-1/2 * (maybe-leaky h) ----------------

template <int C, bool LEAKY>
__launch_bounds__(256)
__global__ void k_agg(const float* __restrict__ h, const int* __restrict__ row_ptr,
                      const int2* __restrict__ csr, const float* __restrict__ dinv,
                      float* __restrict__ out) {
    constexpr int TPN = C / 4;        // threads per node (float4 each)
    constexpr int NPB = 256 / TPN;    // nodes per block
    int node = blockIdx.x * NPB + threadIdx.x / TPN;
    if (node >= NN) return;
    int c = (threadIdx.x % TPN) * 4;
    float di = dinv[node];
    float w0 = di * di;
    float4 hv = *(const float4*)&h[(size_t)node * C + c];
    if (LEAKY) { hv.x = lrelu(hv.x); hv.y = lrelu(hv.y); hv.z = lrelu(hv.z); hv.w = lrelu(hv.w); }
    float4 acc = make_float4(hv.x * w0, hv.y * w0, hv.z * w0, hv.w * w0);
    int e1 = row_ptr[node + 1];
    for (int e = row_ptr[node]; e < e1; ++e) {
        int2 sw = csr[e];
        float w = __int_as_float(sw.y);
        float4 v = *(const float4*)&h[(size_t)sw.x * C + c];
        if (LEAKY) { v.x = lrelu(v.x); v.y = lrelu(v.y); v.z = lrelu(v.z); v.w = lrelu(v.w); }
        acc.x = fmaf(v.x, w, acc.x);
        acc.y = fmaf(v.y, w, acc.y);
        acc.z = fmaf(v.z, w, acc.z);
        acc.w = fmaf(v.w, w, acc.w);
    }
    *(float4*)&out[(size_t)node * C + c] = acc;
}

// ---------------- fp32 GEMM: out[N,128] = A[N,K] @ W[K,128] + b ----------------

template <int K>
__launch_bounds__(256)
__global__ void k_gemm(const float* __restrict__ A, const float* __restrict__ W,
                       const float* __restrict__ bias, float* __restrict__ out) {
    __shared__ float Ws[64 * 128];   // one 64-k chunk of W
    __shared__ float hs[32 * K];     // 32-row tile of A
    constexpr int K4 = K / 4;
    int tid = threadIdx.x;
    int row0 = blockIdx.x * 32;

    for (int i = tid; i < 32 * K4; i += 256) {
        int r = i / K4;
        int gr = row0 + r;
        float4 v = (gr < NN) ? *(const float4*)&A[(size_t)gr * K + (i % K4) * 4]
                             : make_float4(0.f, 0.f, 0.f, 0.f);
        *(float4*)&hs[i * 4] = v;
    }

    int tx = tid & 31, ty = tid >> 5;
    float4 acc[4];
    #pragma unroll
    for (int i = 0; i < 4; i++) acc[i] = make_float4(0.f, 0.f, 0.f, 0.f);

    for (int kb = 0; kb < K; kb += 64) {
        __syncthreads();
        for (int i = tid; i < 64 * 32; i += 256)
            *(float4*)&Ws[i * 4] = *(const float4*)&W[(size_t)kb * 128 + i * 4];
        __syncthreads();

        #pragma unroll
        for (int k0 = 0; k0 < 64; k0 += 4) {
            float4 hr[4], wr[4];
            #pragma unroll
            for (int i = 0; i < 4; i++) hr[i] = *(const float4*)&hs[(ty * 4 + i) * K + kb + k0];
            #pragma unroll
            for (int j = 0; j < 4; j++) wr[j] = *(const float4*)&Ws[(k0 + j) * 128 + tx * 4];
            #pragma unroll
            for (int i = 0; i < 4; i++) {
                acc[i].x = fmaf(hr[i].x, wr[0].x, acc[i].x);
                acc[i].y = fmaf(hr[i].x, wr[0].y, acc[i].y);
                acc[i].z = fmaf(hr[i].x, wr[0].z, acc[i].z);
                acc[i].w = fmaf(hr[i].x, wr[0].w, acc[i].w);
                acc[i].x = fmaf(hr[i].y, wr[1].x, acc[i].x);
                acc[i].y = fmaf(hr[i].y, wr[1].y, acc[i].y);
                acc[i].z = fmaf(hr[i].y, wr[1].z, acc[i].z);
                acc[i].w = fmaf(hr[i].y, wr[1].w, acc[i].w);
                acc[i].x = fmaf(hr[i].z, wr[2].x, acc[i].x);
                acc[i].y = fmaf(hr[i].z, wr[2].y, acc[i].y);
                acc[i].z = fmaf(hr[i].z, wr[2].z, acc[i].z);
                acc[i].w = fmaf(hr[i].z, wr[2].w, acc[i].w);
                acc[i].x = fmaf(hr[i].w, wr[3].x, acc[i].x);
                acc[i].y = fmaf(hr[i].w, wr[3].y, acc[i].y);
                acc[i].z = fmaf(hr[i].w, wr[3].z, acc[i].z);
                acc[i].w = fmaf(hr[i].w, wr[3].w, acc[i].w);
            }
        }
    }

    float4 bv = *(const float4*)&bias[tx * 4];
    #pragma unroll
    for (int i = 0; i < 4; i++) {
        int gr = row0 + ty * 4 + i;
        if (gr < NN)
            *(float4*)&out[(size_t)gr * 128 + tx * 4] =
                make_float4(acc[i].x + bv.x, acc[i].y + bv.y, acc[i].z + bv.z, acc[i].w + bv.w);
    }
}

// ---------------- final: u = leaky(h) @ Wout[128,3] ----------------

__launch_bounds__(256)
__global__ void k_out_gemm(const float* __restrict__ h, const float* __restrict__ Wout,
                           float* __restrict__ u) {
    __shared__ float Ws[128 * 3];
    int tid = threadIdx.x;
    for (int i = tid; i < 384; i += 256) Ws[i] = Wout[i];
    __syncthreads();
    int row = blockIdx.x * 8 + (tid >> 5);
    int lane = tid & 31;
    if (row >= NN) return;
    float4 v = *(const float4*)&h[(size_t)row * 128 + lane * 4];
    v.x = lrelu(v.x); v.y = lrelu(v.y); v.z = lrelu(v.z); v.w = lrelu(v.w);
    int k = lane * 4;
    float a0 = v.x * Ws[k * 3 + 0] + v.y * Ws[(k + 1) * 3 + 0] +
               v.z * Ws[(k + 2) * 3 + 0] + v.w * Ws[(k + 3) * 3 + 0];
    float a1 = v.x * Ws[k * 3 + 1] + v.y * Ws[(k + 1) * 3 + 1] +
               v.z * Ws[(k + 2) * 3 + 1] + v.w * Ws[(k + 3) * 3 + 1];
    float a2 = v.x * Ws[k * 3 + 2] + v.y * Ws[(k + 1) * 3 + 2] +
               v.z * Ws[(k + 2) * 3 + 2] + v.w * Ws[(k + 3) * 3 + 2];
    for (int off = 16; off > 0; off >>= 1) {
        a0 += __shfl_down(a0, off, 32);
        a1 += __shfl_down(a1, off, 32);
        a2 += __shfl_down(a2, off, 32);
    }
    if (lane == 0) {
        u[(size_t)row * 3 + 0] = a0;
        u[(size_t)row * 3 + 1] = a1;
        u[(size_t)row * 3 + 2] = a2;
    }
}

// ---------------- final aggregate (3 ch) + bias + tanh*0.5 ----------------

__global__ void k_agg_out(const float* __restrict__ u, const int* __restrict__ row_ptr,
                          const int2* __restrict__ csr, const float* __restrict__ dinv,
                          const float* __restrict__ bout, float* __restrict__ out) {
    int node = blockIdx.x * 256 + threadIdx.x;
    if (node >= NN) return;
    float di = dinv[node], w0 = di * di;
    float a0 = u[(size_t)node * 3 + 0] * w0;
    float a1 = u[(size_t)node * 3 + 1] * w0;
    float a2 = u[(size_t)node * 3 + 2] * w0;
    int e1 = row_ptr[node + 1];
    for (int e = row_ptr[node]; e < e1; ++e) {
        int2 sw = csr[e];
        float w = __int_as_float(sw.y);
        const float* us = &u[(size_t)sw.x * 3];
        a0 = fmaf(us[0], w, a0);
        a1 = fmaf(us[1], w, a1);
        a2 = fmaf(us[2], w, a2);
    }
    out[(size_t)node * 3 + 0] = tanhf(a0 + bout[0]) * 0.5f;
    out[(size_t)node * 3 + 1] = tanhf(a1 + bout[1]) * 0.5f;
    out[(size_t)node * 3 + 2] = tanhf(a2 + bout[2]) * 0.5f;
}

// ---------------- launch ----------------

extern "C" void kernel_launch(void* const* d_in, const int* in_sizes, int n_in,
                              void* d_out, int out_size, void* d_ws, size_t ws_size,
                              hipStream_t stream) {
    const float* x        = (const float*)d_in[0];
    const int*   ei       = (const int*)d_in[1];   // int32: [2, NE] row-major
    const float* W0       = (const float*)d_in[2];
    const float* b0       = (const float*)d_in[3];
    const float* Wh       = (const float*)d_in[4];
    const float* bh       = (const float*)d_in[5];
    const float* Wout     = (const float*)d_in[6];
    const float* bout     = (const float*)d_in[7];
    float* out            = (float*)d_out;

    char* ws = (char*)d_ws;
    float* bufA   = (float*)(ws + 0);              // NN*128 floats = 15,360,000 B
    float* bufB   = (float*)(ws + 15360000);       // NN*128 floats
    float* dinv   = (float*)(ws + 30720000);       // NN floats
    int*   cnt    = (int*)  (ws + 30840000);       // NN ints
    int*   row_ptr= (int*)  (ws + 30960000);       // NN+1 ints (padded)
    int*   cursor = (int*)  (ws + 31080064);       // NN ints
    int2*  csr    = (int2*) (ws + 31200064);       // NE int2 = 3,840,000 B

    // scan temporaries: borrow bufA space (unused until after CSR build)
    int* bsum = (int*)bufA;        // NB ints
    int* boff = bsum + 256;        // NB ints

    hipMemsetAsync(cnt, 0, NN * sizeof(int), stream);
    k_count<<<(NE + 255) / 256, 256, 0, stream>>>(ei, cnt);
    k_scan1<<<NB, 256, 0, stream>>>(cnt, bsum, dinv);
    k_scan2<<<1, 128, 0, stream>>>(bsum, boff);
    k_scan3<<<NB, 256, 0, stream>>>(cnt, boff, row_ptr, cursor);
    k_fill<<<(NE + 255) / 256, 256, 0, stream>>>(ei, dinv, cursor, csr);

    // layer 0: h1 = (A_hat x) @ W0 + b0     (aggregate-first: 64ch gather)
    k_agg<64, false><<<NN / 16, 256, 0, stream>>>(x, row_ptr, csr, dinv, bufA);
    k_gemm<64><<<(NN + 31) / 32, 256, 0, stream>>>(bufA, W0, b0, bufB);

    // hidden layers: h = (A_hat leaky(h)) @ Wh[i] + bh[i]
    for (int i = 0; i < 6; i++) {
        k_agg<128, true><<<NN / 8, 256, 0, stream>>>(bufB, row_ptr, csr, dinv, bufA);
        k_gemm<128><<<(NN + 31) / 32, 256, 0, stream>>>(bufA, Wh + (size_t)i * 128 * 128,
                                                        bh + (size_t)i * 128, bufB);
    }

    // final: out = tanh(A_hat (leaky(h) @ Wout) + bout) * 0.5   (GEMM-first: 3ch gather)
    k_out_gemm<<<(NN + 7) / 8, 256, 0, stream>>>(bufB, Wout, bufA /* u: NN x 3 */);
    k_agg_out<<<(NN + 255) / 256, 256, 0, stream>>>(bufA, row_ptr, csr, dinv, bout, out);
}

// Round 4
// 536.287 us; speedup vs baseline: 1.1835x; 1.1008x over previous
//
#include <hip/hip_runtime.h>
#include <math.h>

#define NN 30000
#define NE 480000
#define NB 118  // ceil(NN/256)

__device__ __forceinline__ float lrelu(float v) { return v > 0.0f ? v : v * 0.02f; }

__device__ __forceinline__ float4 fma4(float4 v, float w, float4 a) {
    a.x = fmaf(v.x, w, a.x);
    a.y = fmaf(v.y, w, a.y);
    a.z = fmaf(v.z, w, a.z);
    a.w = fmaf(v.w, w, a.w);
    return a;
}

// ---------------- CSR build ----------------

__global__ void k_count(const int* __restrict__ ei, int* __restrict__ cnt) {
    int e = blockIdx.x * 256 + threadIdx.x;
    if (e < NE) atomicAdd(&cnt[ei[NE + e]], 1);
}

// phase 1: per-block totals of cnt, plus dinv (fused)
__global__ void k_scan1(const int* __restrict__ cnt, int* __restrict__ bsum,
                        float* __restrict__ dinv) {
    __shared__ int sd[256];
    int tid = threadIdx.x;
    int i = blockIdx.x * 256 + tid;
    int v = (i < NN) ? cnt[i] : 0;
    if (i < NN) dinv[i] = 1.0f / sqrtf((float)(v + 1));  // +1 self loop
    sd[tid] = v;
    __syncthreads();
    for (int off = 128; off > 0; off >>= 1) {
        if (tid < off) sd[tid] += sd[tid + off];
        __syncthreads();
    }
    if (tid == 0) bsum[blockIdx.x] = sd[0];
}

// phase 2: exclusive scan of NB block sums (single tiny block)
__global__ void k_scan2(const int* __restrict__ bsum, int* __restrict__ boff) {
    __shared__ int sd[128];
    int tid = threadIdx.x;  // 128 threads >= NB
    int v = (tid < NB) ? bsum[tid] : 0;
    sd[tid] = v;
    __syncthreads();
    for (int off = 1; off < 128; off <<= 1) {
        int t = (tid >= off) ? sd[tid - off] : 0;
        __syncthreads();
        sd[tid] += t;
        __syncthreads();
    }
    if (tid < NB) boff[tid] = sd[tid] - v;  // exclusive
}

// phase 3: within-block inclusive scan + offset -> row_ptr/cursor
__global__ void k_scan3(const int* __restrict__ cnt, const int* __restrict__ boff,
                        int* __restrict__ row_ptr, int* __restrict__ cursor) {
    __shared__ int sd[256];
    int tid = threadIdx.x;
    int i = blockIdx.x * 256 + tid;
    int v = (i < NN) ? cnt[i] : 0;
    sd[tid] = v;
    __syncthreads();
    for (int off = 1; off < 256; off <<= 1) {
        int t = (tid >= off) ? sd[tid - off] : 0;
        __syncthreads();
        sd[tid] += t;
        __syncthreads();
    }
    if (i < NN) {
        int excl = boff[blockIdx.x] + sd[tid] - v;
        row_ptr[i] = excl;
        cursor[i] = excl;
        if (i == NN - 1) row_ptr[NN] = excl + v;
    }
}

__global__ void k_fill(const int* __restrict__ ei, const float* __restrict__ dinv,
                       int* __restrict__ cursor, int2* __restrict__ csr) {
    int e = blockIdx.x * 256 + threadIdx.x;
    if (e < NE) {
        int s = ei[e];
        int d = ei[NE + e];
        int pos = atomicAdd(&cursor[d], 1);
        float w = dinv[s] * dinv[d];
        csr[pos] = make_int2(s, __float_as_int(w));
    }
}

// ---------------- aggregation: out = D^-1/2 (A+I) D^-1/2 * h ----------------
// h is already post-activation (lrelu folded into producer GEMM epilogue).
// Edge loop unrolled x4 with independent accumulators for memory-level parallelism.

template <int C>
__launch_bounds__(256)
__global__ void k_agg(const float* __restrict__ h, const int* __restrict__ row_ptr,
                      const int2* __restrict__ csr, const float* __restrict__ dinv,
                      float* __restrict__ out) {
    constexpr int TPN = C / 4;        // threads per node (float4 each)
    constexpr int NPB = 256 / TPN;    // nodes per block
    int node = blockIdx.x * NPB + threadIdx.x / TPN;
    if (node >= NN) return;
    int c = (threadIdx.x % TPN) * 4;
    float di = dinv[node];
    float w0 = di * di;
    float4 hv = *(const float4*)&h[(size_t)node * C + c];
    float4 acc0 = make_float4(hv.x * w0, hv.y * w0, hv.z * w0, hv.w * w0);
    float4 acc1 = make_float4(0.f, 0.f, 0.f, 0.f);
    float4 acc2 = make_float4(0.f, 0.f, 0.f, 0.f);
    float4 acc3 = make_float4(0.f, 0.f, 0.f, 0.f);
    int e = row_ptr[node];
    int e1 = row_ptr[node + 1];
    for (; e + 4 <= e1; e += 4) {
        int2 sw0 = csr[e + 0];
        int2 sw1 = csr[e + 1];
        int2 sw2 = csr[e + 2];
        int2 sw3 = csr[e + 3];
        float4 v0 = *(const float4*)&h[(size_t)sw0.x * C + c];
        float4 v1 = *(const float4*)&h[(size_t)sw1.x * C + c];
        float4 v2 = *(const float4*)&h[(size_t)sw2.x * C + c];
        float4 v3 = *(const float4*)&h[(size_t)sw3.x * C + c];
        acc0 = fma4(v0, __int_as_float(sw0.y), acc0);
        acc1 = fma4(v1, __int_as_float(sw1.y), acc1);
        acc2 = fma4(v2, __int_as_float(sw2.y), acc2);
        acc3 = fma4(v3, __int_as_float(sw3.y), acc3);
    }
    for (; e < e1; ++e) {
        int2 sw = csr[e];
        float4 v = *(const float4*)&h[(size_t)sw.x * C + c];
        acc0 = fma4(v, __int_as_float(sw.y), acc0);
    }
    acc0.x = (acc0.x + acc1.x) + (acc2.x + acc3.x);
    acc0.y = (acc0.y + acc1.y) + (acc2.y + acc3.y);
    acc0.z = (acc0.z + acc1.z) + (acc2.z + acc3.z);
    acc0.w = (acc0.w + acc1.w) + (acc2.w + acc3.w);
    *(float4*)&out[(size_t)node * C + c] = acc0;
}

// ---------------- fp32 GEMM: out[N,128] = lrelu(A[N,K] @ W[K,128] + b) ----------------

template <int K>
__launch_bounds__(256)
__global__ void k_gemm(const float* __restrict__ A, const float* __restrict__ W,
                       const float* __restrict__ bias, float* __restrict__ out) {
    __shared__ float Ws[64 * 128];   // one 64-k chunk of W
    __shared__ float hs[32 * K];     // 32-row tile of A
    constexpr int K4 = K / 4;
    int tid = threadIdx.x;
    int row0 = blockIdx.x * 32;

    for (int i = tid; i < 32 * K4; i += 256) {
        int r = i / K4;
        int gr = row0 + r;
        float4 v = (gr < NN) ? *(const float4*)&A[(size_t)gr * K + (i % K4) * 4]
                             : make_float4(0.f, 0.f, 0.f, 0.f);
        *(float4*)&hs[i * 4] = v;
    }

    int tx = tid & 31, ty = tid >> 5;
    float4 acc[4];
    #pragma unroll
    for (int i = 0; i < 4; i++) acc[i] = make_float4(0.f, 0.f, 0.f, 0.f);

    for (int kb = 0; kb < K; kb += 64) {
        __syncthreads();
        for (int i = tid; i < 64 * 32; i += 256)
            *(float4*)&Ws[i * 4] = *(const float4*)&W[(size_t)kb * 128 + i * 4];
        __syncthreads();

        #pragma unroll
        for (int k0 = 0; k0 < 64; k0 += 4) {
            float4 hr[4], wr[4];
            #pragma unroll
            for (int i = 0; i < 4; i++) hr[i] = *(const float4*)&hs[(ty * 4 + i) * K + kb + k0];
            #pragma unroll
            for (int j = 0; j < 4; j++) wr[j] = *(const float4*)&Ws[(k0 + j) * 128 + tx * 4];
            #pragma unroll
            for (int i = 0; i < 4; i++) {
                acc[i].x = fmaf(hr[i].x, wr[0].x, acc[i].x);
                acc[i].y = fmaf(hr[i].x, wr[0].y, acc[i].y);
                acc[i].z = fmaf(hr[i].x, wr[0].z, acc[i].z);
                acc[i].w = fmaf(hr[i].x, wr[0].w, acc[i].w);
                acc[i].x = fmaf(hr[i].y, wr[1].x, acc[i].x);
                acc[i].y = fmaf(hr[i].y, wr[1].y, acc[i].y);
                acc[i].z = fmaf(hr[i].y, wr[1].z, acc[i].z);
                acc[i].w = fmaf(hr[i].y, wr[1].w, acc[i].w);
                acc[i].x = fmaf(hr[i].z, wr[2].x, acc[i].x);
                acc[i].y = fmaf(hr[i].z, wr[2].y, acc[i].y);
                acc[i].z = fmaf(hr[i].z, wr[2].z, acc[i].z);
                acc[i].w = fmaf(hr[i].z, wr[2].w, acc[i].w);
                acc[i].x = fmaf(hr[i].w, wr[3].x, acc[i].x);
                acc[i].y = fmaf(hr[i].w, wr[3].y, acc[i].y);
                acc[i].z = fmaf(hr[i].w, wr[3].z, acc[i].z);
                acc[i].w = fmaf(hr[i].w, wr[3].w, acc[i].w);
            }
        }
    }

    float4 bv = *(const float4*)&bias[tx * 4];
    #pragma unroll
    for (int i = 0; i < 4; i++) {
        int gr = row0 + ty * 4 + i;
        if (gr < NN) {
            float4 r = make_float4(lrelu(acc[i].x + bv.x), lrelu(acc[i].y + bv.y),
                                   lrelu(acc[i].z + bv.z), lrelu(acc[i].w + bv.w));
            *(float4*)&out[(size_t)gr * 128 + tx * 4] = r;
        }
    }
}

// ---------------- final: u = h @ Wout[128,3]  (h already post-activation) ----------------

__launch_bounds__(256)
__global__ void k_out_gemm(const float* __restrict__ h, const float* __restrict__ Wout,
                           float* __restrict__ u) {
    __shared__ float Ws[128 * 3];
    int tid = threadIdx.x;
    for (int i = tid; i < 384; i += 256) Ws[i] = Wout[i];
    __syncthreads();
    int row = blockIdx.x * 8 + (tid >> 5);
    int lane = tid & 31;
    if (row >= NN) return;
    float4 v = *(const float4*)&h[(size_t)row * 128 + lane * 4];
    int k = lane * 4;
    float a0 = v.x * Ws[k * 3 + 0] + v.y * Ws[(k + 1) * 3 + 0] +
               v.z * Ws[(k + 2) * 3 + 0] + v.w * Ws[(k + 3) * 3 + 0];
    float a1 = v.x * Ws[k * 3 + 1] + v.y * Ws[(k + 1) * 3 + 1] +
               v.z * Ws[(k + 2) * 3 + 1] + v.w * Ws[(k + 3) * 3 + 1];
    float a2 = v.x * Ws[k * 3 + 2] + v.y * Ws[(k + 1) * 3 + 2] +
               v.z * Ws[(k + 2) * 3 + 2] + v.w * Ws[(k + 3) * 3 + 2];
    for (int off = 16; off > 0; off >>= 1) {
        a0 += __shfl_down(a0, off, 32);
        a1 += __shfl_down(a1, off, 32);
        a2 += __shfl_down(a2, off, 32);
    }
    if (lane == 0) {
        u[(size_t)row * 3 + 0] = a0;
        u[(size_t)row * 3 + 1] = a1;
        u[(size_t)row * 3 + 2] = a2;
    }
}

// ---------------- final aggregate (3 ch) + bias + tanh*0.5 ----------------

__global__ void k_agg_out(const float* __restrict__ u, const int* __restrict__ row_ptr,
                          const int2* __restrict__ csr, const float* __restrict__ dinv,
                          const float* __restrict__ bout, float* __restrict__ out) {
    int node = blockIdx.x * 256 + threadIdx.x;
    if (node >= NN) return;
    float di = dinv[node], w0 = di * di;
    float s0 = u[(size_t)node * 3 + 0] * w0;
    float s1 = u[(size_t)node * 3 + 1] * w0;
    float s2 = u[(size_t)node * 3 + 2] * w0;
    float b0a = 0.f, b1a = 0.f, b2a = 0.f;
    int e = row_ptr[node];
    int e1 = row_ptr[node + 1];
    for (; e + 2 <= e1; e += 2) {
        int2 swa = csr[e], swb = csr[e + 1];
        float wa = __int_as_float(swa.y), wb = __int_as_float(swb.y);
        const float* ua = &u[(size_t)swa.x * 3];
        const float* ub = &u[(size_t)swb.x * 3];
        s0 = fmaf(ua[0], wa, s0);
        s1 = fmaf(ua[1], wa, s1);
        s2 = fmaf(ua[2], wa, s2);
        b0a = fmaf(ub[0], wb, b0a);
        b1a = fmaf(ub[1], wb, b1a);
        b2a = fmaf(ub[2], wb, b2a);
    }
    for (; e < e1; ++e) {
        int2 sw = csr[e];
        float w = __int_as_float(sw.y);
        const float* us = &u[(size_t)sw.x * 3];
        s0 = fmaf(us[0], w, s0);
        s1 = fmaf(us[1], w, s1);
        s2 = fmaf(us[2], w, s2);
    }
    out[(size_t)node * 3 + 0] = tanhf(s0 + b0a + bout[0]) * 0.5f;
    out[(size_t)node * 3 + 1] = tanhf(s1 + b1a + bout[1]) * 0.5f;
    out[(size_t)node * 3 + 2] = tanhf(s2 + b2a + bout[2]) * 0.5f;
}

// ---------------- launch ----------------

extern "C" void kernel_launch(void* const* d_in, const int* in_sizes, int n_in,
                              void* d_out, int out_size, void* d_ws, size_t ws_size,
                              hipStream_t stream) {
    const float* x        = (const float*)d_in[0];
    const int*   ei       = (const int*)d_in[1];   // int32: [2, NE] row-major
    const float* W0       = (const float*)d_in[2];
    const float* b0       = (const float*)d_in[3];
    const float* Wh       = (const float*)d_in[4];
    const float* bh       = (const float*)d_in[5];
    const float* Wout     = (const float*)d_in[6];
    const float* bout     = (const float*)d_in[7];
    float* out            = (float*)d_out;

    char* ws = (char*)d_ws;
    float* bufA   = (float*)(ws + 0);              // NN*128 floats = 15,360,000 B
    float* bufB   = (float*)(ws + 15360000);       // NN*128 floats
    float* dinv   = (float*)(ws + 30720000);       // NN floats
    int*   cnt    = (int*)  (ws + 30840000);       // NN ints
    int*   row_ptr= (int*)  (ws + 30960000);       // NN+1 ints (padded)
    int*   cursor = (int*)  (ws + 31080064);       // NN ints
    int2*  csr    = (int2*) (ws + 31200064);       // NE int2 = 3,840,000 B

    // scan temporaries: borrow bufA space (unused until after CSR build)
    int* bsum = (int*)bufA;        // NB ints
    int* boff = bsum + 256;        // NB ints

    hipMemsetAsync(cnt, 0, NN * sizeof(int), stream);
    k_count<<<(NE + 255) / 256, 256, 0, stream>>>(ei, cnt);
    k_scan1<<<NB, 256, 0, stream>>>(cnt, bsum, dinv);
    k_scan2<<<1, 128, 0, stream>>>(bsum, boff);
    k_scan3<<<NB, 256, 0, stream>>>(cnt, boff, row_ptr, cursor);
    k_fill<<<(NE + 255) / 256, 256, 0, stream>>>(ei, dinv, cursor, csr);

    // layer 0: h1 = lrelu((A_hat x) @ W0 + b0)   (aggregate-first: 64ch gather; x is raw)
    k_agg<64><<<NN / 16, 256, 0, stream>>>(x, row_ptr, csr, dinv, bufA);
    k_gemm<64><<<(NN + 31) / 32, 256, 0, stream>>>(bufA, W0, b0, bufB);

    // hidden layers: h = lrelu((A_hat h) @ Wh[i] + bh[i])   (h already activated)
    for (int i = 0; i < 6; i++) {
        k_agg<128><<<NN / 8, 256, 0, stream>>>(bufB, row_ptr, csr, dinv, bufA);
        k_gemm<128><<<(NN + 31) / 32, 256, 0, stream>>>(bufA, Wh + (size_t)i * 128 * 128,
                                                        bh + (size_t)i * 128, bufB);
    }

    // final: out = tanh(A_hat (h @ Wout) + bout) * 0.5   (GEMM-first: 3ch gather)
    k_out_gemm<<<(NN + 7) / 8, 256, 0, stream>>>(bufB, Wout, bufA /* u: NN x 3 */);
    k_agg_out<<<(NN + 255) / 256, 256, 0, stream>>>(bufA, row_ptr, csr, dinv, bout, out);
}